// Round 12
// baseline (36.477 us; speedup 1.0000x reference)
//
#include <hip/hip_runtime.h>

#define HW       262144      // 512*512 elements per image plane
#define NBINS    10
#define NBLOCKS  2048

// d_ws: 20 cumulative quantities * NBLOCKS per-block slots (fp32), plain
// stores (every slot written every call -> no memset needed):
//   ws[q*2048 + block], q in [0,10)  : C[k] = count of (valid & g >= k/10)
//   ws[q*2048 + block], q in [10,20) : S[k] = weighted-log sum where g >= k/10
// C[0] == valid total.

__global__ __launch_bounds__(256) void ghm_accum(
    const float* __restrict__ pred, const float* __restrict__ target,
    float* __restrict__ ws)
{
    __shared__ float shred[4][32];     // per-wave partials

    const int tid  = threadIdx.x;
    const int lane = tid & 63;
    const int wv   = tid >> 6;

    // 2048 blocks: 64 blocks per image, each block owns 1024 consecutive vec4s
    const int img = blockIdx.x >> 6;
    const int v0  = (blockIdx.x & 63) * 1024 + tid;

    const float* pp = pred   + (size_t)img * HW;
    const float* th = target + (size_t)img * (3 * HW);

    float4 p4[4], hm4[4], vl4[4], ps4[4];
    #pragma unroll
    for (int k = 0; k < 4; ++k) {
        const int r = (v0 + (k << 8)) << 2;
        p4[k]  = *reinterpret_cast<const float4*>(pp + r);
        hm4[k] = *reinterpret_cast<const float4*>(th + r);
        vl4[k] = *reinterpret_cast<const float4*>(th + HW + r);
        ps4[k] = *reinterpret_cast<const float4*>(th + 2 * HW + r);
    }

    float ck[NBINS], sk[NBINS];
    #pragma unroll
    for (int b = 0; b < NBINS; ++b) { ck[b] = 0.f; sk[b] = 0.f; }

    #pragma unroll
    for (int k = 0; k < 4; ++k) {
        #pragma unroll
        for (int j = 0; j < 4; ++j) {
            const float p  = (&p4[k].x)[j];
            const float hm = (&hm4[k].x)[j];
            const float vl = (&vl4[k].x)[j];   // 0.0 or 1.0
            const float ps = (&ps4[k].x)[j];   // 0.0 or 1.0, ps <= vl

            // p in (1e-4, 1-1e-4) => g = |p*vl - ps| < 1 strictly, so
            // in_bin == valid == (vl > 0); count-of-valid == tot.
            const float g  = fabsf(__builtin_fmaf(p, vl, -ps));
            const bool isP = (ps != 0.f);

            const float x  = isP ? p : 1.f - p;
            const float l  = __logf(x);
            const float t  = 1.f - hm;
            const float t2 = t * t;
            const float nw = t2 * t2;                    // (1-hm)^4
            const float lfac = vl * (isP ? l : l * nw);  // masked by valid

            ck[0] += vl;
            sk[0] += lfac;
            #pragma unroll
            for (int b = 1; b < NBINS; ++b) {
                const float edge = (b == 1) ? 0.1f : (b == 2) ? 0.2f :
                                   (b == 3) ? 0.3f : (b == 4) ? 0.4f :
                                   (b == 5) ? 0.5f : (b == 6) ? 0.6f :
                                   (b == 7) ? 0.7f : (b == 8) ? 0.8f : 0.9f;
                const float sel = (g >= edge) ? 1.f : 0.f;
                ck[b] = __builtin_fmaf(sel, vl,   ck[b]);
                sk[b] = __builtin_fmaf(sel, lfac, sk[b]);
            }
        }
    }

    // 64-lane butterfly reduce of the 20 register accumulators
    #pragma unroll
    for (int off = 32; off; off >>= 1) {
        #pragma unroll
        for (int b = 0; b < NBINS; ++b) {
            ck[b] += __shfl_xor(ck[b], off);
            sk[b] += __shfl_xor(sk[b], off);
        }
    }

    if (lane == 0) {
        #pragma unroll
        for (int b = 0; b < NBINS; ++b) {
            shred[wv][b]      = ck[b];
            shred[wv][10 + b] = sk[b];
        }
    }
    __syncthreads();

    // plain per-block store (no atomic, no memset dependency)
    if (tid < 20) {
        const float s = shred[0][tid] + shred[1][tid] +
                        shred[2][tid] + shred[3][tid];
        ws[tid * NBLOCKS + blockIdx.x] = s;
    }
}

__global__ __launch_bounds__(640) void ghm_final(
    const float* __restrict__ ws, float* __restrict__ out)
{
    __shared__ float qsh[20];
    const int tid = threadIdx.x;
    const int q   = tid >> 5;          // 20 groups of 32 threads
    const int sl  = tid & 31;

    float s = 0.f;
    #pragma unroll
    for (int k = 0; k < 64; ++k)       // coalesced: 64 consecutive per thread
        s += ws[q * NBLOCKS + sl * 64 + k];

    #pragma unroll
    for (int off = 16; off; off >>= 1) s += __shfl_down(s, off, 32);
    if (sl == 0) qsh[q] = s;
    __syncthreads();

    if (tid == 0) {
        float tot = qsh[0];            // C[0] == valid count
        if (tot < 1.f) tot = 1.f;

        float cnt_b[NBINS], sv[NBINS];
        for (int b = 0; b < NBINS - 1; ++b) {
            cnt_b[b] = qsh[b]      - qsh[b + 1];
            sv[b]    = qsh[10 + b] - qsh[11 + b];
        }
        cnt_b[NBINS - 1] = qsh[NBINS - 1];
        sv[NBINS - 1]    = qsh[19];

        int nne = 0;
        for (int b = 0; b < NBINS; ++b) if (cnt_b[b] > 0.f) nne++;
        const float nn = (nne > 0) ? (float)nne : 1.f;

        float s2 = 0.f;
        for (int b = 0; b < NBINS; ++b) {
            const float w = (cnt_b[b] > 0.f) ? (tot / fmaxf(cnt_b[b], 1.f)) / nn
                                             : 0.f;
            s2 += sv[b] * w;
        }
        out[0] = -s2 / tot;
    }
}

extern "C" void kernel_launch(void* const* d_in, const int* in_sizes, int n_in,
                              void* d_out, int out_size, void* d_ws, size_t ws_size,
                              hipStream_t stream)
{
    const float* pred   = (const float*)d_in[0];
    const float* target = (const float*)d_in[1];
    float*       out    = (float*)d_out;
    float*       ws     = (float*)d_ws;

    ghm_accum<<<NBLOCKS, 256, 0, stream>>>(pred, target, ws);
    ghm_final<<<1, 640, 0, stream>>>(ws, out);
}

// Round 13
// 33.359 us; speedup vs baseline: 1.0935x; 1.0935x over previous
//
#include <hip/hip_runtime.h>

#define HW       262144      // 512*512 elements per image plane
#define NBINS    10
#define NBLOCKS  1024

// d_ws: 20 cumulative quantities * NBLOCKS per-block slots (fp32), plain
// stores (every slot written every call -> no memset needed):
//   ws[q*1024 + block], q in [0,10)  : C[k] = count of (valid & g >= k/10)
//   ws[q*1024 + block], q in [10,20) : S[k] = weighted-log sum where g >= k/10
// C[0] == valid total.

__global__ __launch_bounds__(256) void ghm_accum(
    const float* __restrict__ pred, const float* __restrict__ target,
    float* __restrict__ ws)
{
    __shared__ float shred[4][32];     // per-wave partials

    const int tid  = threadIdx.x;
    const int lane = tid & 63;
    const int wv   = tid >> 6;

    // 1024 blocks: 32 blocks per image, each block owns 2048 consecutive vec4s
    const int img      = blockIdx.x >> 5;
    const int tileBase = (blockIdx.x & 31) * 2048;

    const float* pp = pred   + (size_t)img * HW;
    const float* th = target + (size_t)img * (3 * HW);

    float ck[NBINS], sk[NBINS];
    #pragma unroll
    for (int b = 0; b < NBINS; ++b) { ck[b] = 0.f; sk[b] = 0.f; }

    #pragma unroll 1
    for (int c = 0; c < 2; ++c) {
        const int v0 = tileBase + c * 1024 + tid;

        float4 p4[4], hm4[4], vl4[4], ps4[4];
        #pragma unroll
        for (int k = 0; k < 4; ++k) {
            const int r = (v0 + (k << 8)) << 2;
            p4[k]  = *reinterpret_cast<const float4*>(pp + r);
            hm4[k] = *reinterpret_cast<const float4*>(th + r);
            vl4[k] = *reinterpret_cast<const float4*>(th + HW + r);
            ps4[k] = *reinterpret_cast<const float4*>(th + 2 * HW + r);
        }

        #pragma unroll
        for (int k = 0; k < 4; ++k) {
            #pragma unroll
            for (int j = 0; j < 4; ++j) {
                const float p  = (&p4[k].x)[j];
                const float hm = (&hm4[k].x)[j];
                const float vl = (&vl4[k].x)[j];   // 0.0 or 1.0
                const float ps = (&ps4[k].x)[j];   // 0.0 or 1.0, ps <= vl

                // p in (1e-4, 1-1e-4) => g = |p*vl - ps| < 1 strictly, so
                // in_bin == valid == (vl > 0); count-of-valid == tot.
                const float g  = fabsf(__builtin_fmaf(p, vl, -ps));
                const bool isP = (ps != 0.f);

                const float x  = isP ? p : 1.f - p;
                const float l  = __logf(x);
                const float t  = 1.f - hm;
                const float t2 = t * t;
                const float nw = t2 * t2;                    // (1-hm)^4
                const float lfac = vl * (isP ? l : l * nw);  // masked by valid

                ck[0] += vl;
                sk[0] += lfac;
                #pragma unroll
                for (int b = 1; b < NBINS; ++b) {
                    const float edge = (b == 1) ? 0.1f : (b == 2) ? 0.2f :
                                       (b == 3) ? 0.3f : (b == 4) ? 0.4f :
                                       (b == 5) ? 0.5f : (b == 6) ? 0.6f :
                                       (b == 7) ? 0.7f : (b == 8) ? 0.8f : 0.9f;
                    const float sel = (g >= edge) ? 1.f : 0.f;
                    ck[b] = __builtin_fmaf(sel, vl,   ck[b]);
                    sk[b] = __builtin_fmaf(sel, lfac, sk[b]);
                }
            }
        }
    }

    // 64-lane butterfly reduce of the 20 register accumulators
    #pragma unroll
    for (int off = 32; off; off >>= 1) {
        #pragma unroll
        for (int b = 0; b < NBINS; ++b) {
            ck[b] += __shfl_xor(ck[b], off);
            sk[b] += __shfl_xor(sk[b], off);
        }
    }

    if (lane == 0) {
        #pragma unroll
        for (int b = 0; b < NBINS; ++b) {
            shred[wv][b]      = ck[b];
            shred[wv][10 + b] = sk[b];
        }
    }
    __syncthreads();

    // plain per-block store (no atomic, no memset dependency)
    if (tid < 20) {
        const float s = shred[0][tid] + shred[1][tid] +
                        shred[2][tid] + shred[3][tid];
        ws[tid * NBLOCKS + blockIdx.x] = s;
    }
}

__global__ __launch_bounds__(640) void ghm_final(
    const float* __restrict__ ws, float* __restrict__ out)
{
    __shared__ float qsh[20];
    const int tid = threadIdx.x;
    const int q   = tid >> 5;          // 20 groups of 32 threads
    const int sl  = tid & 31;

    float s = 0.f;
    #pragma unroll
    for (int k = 0; k < 32; ++k)       // coalesced: 32 consecutive per thread
        s += ws[q * NBLOCKS + sl * 32 + k];

    #pragma unroll
    for (int off = 16; off; off >>= 1) s += __shfl_down(s, off, 32);
    if (sl == 0) qsh[q] = s;
    __syncthreads();

    if (tid == 0) {
        float tot = qsh[0];            // C[0] == valid count
        if (tot < 1.f) tot = 1.f;

        float cnt_b[NBINS], sv[NBINS];
        for (int b = 0; b < NBINS - 1; ++b) {
            cnt_b[b] = qsh[b]      - qsh[b + 1];
            sv[b]    = qsh[10 + b] - qsh[11 + b];
        }
        cnt_b[NBINS - 1] = qsh[NBINS - 1];
        sv[NBINS - 1]    = qsh[19];

        int nne = 0;
        for (int b = 0; b < NBINS; ++b) if (cnt_b[b] > 0.f) nne++;
        const float nn = (nne > 0) ? (float)nne : 1.f;

        float s2 = 0.f;
        for (int b = 0; b < NBINS; ++b) {
            const float w = (cnt_b[b] > 0.f) ? (tot / fmaxf(cnt_b[b], 1.f)) / nn
                                             : 0.f;
            s2 += sv[b] * w;
        }
        out[0] = -s2 / tot;
    }
}

extern "C" void kernel_launch(void* const* d_in, const int* in_sizes, int n_in,
                              void* d_out, int out_size, void* d_ws, size_t ws_size,
                              hipStream_t stream)
{
    const float* pred   = (const float*)d_in[0];
    const float* target = (const float*)d_in[1];
    float*       out    = (float*)d_out;
    float*       ws     = (float*)d_ws;

    ghm_accum<<<NBLOCKS, 256, 0, stream>>>(pred, target, ws);
    ghm_final<<<1, 640, 0, stream>>>(ws, out);
}